// Round 1
// baseline (189.450 us; speedup 1.0000x reference)
//
#include <hip/hip_runtime.h>

typedef __bf16 bf16x8 __attribute__((ext_vector_type(8)));
typedef float f32x4 __attribute__((ext_vector_type(4)));
typedef unsigned short u16x8 __attribute__((ext_vector_type(8)));

union FragU { u16x8 u; bf16x8 b; };

__device__ __forceinline__ unsigned short f2bf(float f) {
  unsigned int u = __float_as_uint(f);
  u += 0x7FFFu + ((u >> 16) & 1u);
  return (unsigned short)(u >> 16);
}

#define MFMA16(a, b, c) __builtin_amdgcn_mfma_f32_16x16x32_bf16((a), (b), (c), 0, 0, 0)

// ---------------- W transpose: W[1024][64] f32 -> WT[3][64][1024] bf16 ----------------
__global__ __launch_bounds__(256) void wt_kernel(
    const float* __restrict__ Wq, const float* __restrict__ Wk, const float* __restrict__ Wv,
    unsigned short* __restrict__ WT)
{
  const int h = blockIdx.x & 63;
  const int mtx = blockIdx.x >> 6;  // 0..2
  const float* W = (mtx == 0) ? Wq : ((mtx == 1) ? Wk : Wv);
  for (int d = threadIdx.x; d < 1024; d += 256)
    WT[(size_t)(mtx * 64 + h) * 1024 + d] = f2bf(W[(size_t)d * 64 + h]);
}

// ---------------- QKV projection ----------------
// Q[b][q][64] bf16 (pre-scaled by 1/8), K[b][k][64] bf16, VT[b][h][4096] bf16
__global__ __launch_bounds__(256) void proj_kernel(
    const float* __restrict__ x, const unsigned short* __restrict__ WT,
    const float* __restrict__ bq, const float* __restrict__ bk, const float* __restrict__ bv,
    unsigned short* __restrict__ Qb, unsigned short* __restrict__ Kb,
    unsigned short* __restrict__ VT)
{
  const int tid = threadIdx.x;
  const int lane = tid & 63;
  const int wid = tid >> 6;       // wave 0..3
  const int l15 = lane & 15;
  const int g = lane >> 4;        // 0..3
  const int row0 = blockIdx.x * 64 + wid * 16;

  f32x4 accQ[4], accK[4], accV[4];
  const f32x4 zero = {0.f, 0.f, 0.f, 0.f};
#pragma unroll
  for (int i = 0; i < 4; ++i) { accQ[i] = zero; accK[i] = zero; accV[i] = zero; }

  const float* xrow = x + (size_t)(row0 + l15) * 1024;
  const unsigned short* WqT = WT;
  const unsigned short* WkT = WT + 64 * 1024;
  const unsigned short* WvT = WT + 128 * 1024;

  for (int c = 0; c < 32; ++c) {
    const int d0 = 32 * c + 8 * g;
    f32x4 x0 = *(const f32x4*)(xrow + d0);
    f32x4 x1 = *(const f32x4*)(xrow + d0 + 4);
    FragU xf;
#pragma unroll
    for (int i = 0; i < 4; ++i) { xf.u[i] = f2bf(x0[i]); xf.u[4 + i] = f2bf(x1[i]); }
    bf16x8 wq[4], wk[4], wvf[4];
#pragma unroll
    for (int t = 0; t < 4; ++t) {
      wq[t]  = *(const bf16x8*)(WqT + (size_t)(16 * t + l15) * 1024 + d0);
      wk[t]  = *(const bf16x8*)(WkT + (size_t)(16 * t + l15) * 1024 + d0);
      wvf[t] = *(const bf16x8*)(WvT + (size_t)(16 * t + l15) * 1024 + d0);
    }
#pragma unroll
    for (int t = 0; t < 4; ++t) {
      accQ[t] = MFMA16(xf.b, wq[t], accQ[t]);   // C[q][h]
      accK[t] = MFMA16(xf.b, wk[t], accK[t]);   // C[k][h]
      accV[t] = MFMA16(wvf[t], xf.b, accV[t]);  // C[h][row] = V^T
    }
  }

  const int b = row0 >> 12;
  const int q0 = row0 & 4095;
  unsigned short* Qbase = Qb + (size_t)b * 4096 * 64;
  unsigned short* Kbase = Kb + (size_t)b * 4096 * 64;
  unsigned short* Vbase = VT + (size_t)b * 64 * 4096;
#pragma unroll
  for (int t = 0; t < 4; ++t) {
    const int h = 16 * t + l15;
    const float bqv = bq[h];
    const float bkv = bk[h];
#pragma unroll
    for (int r = 0; r < 4; ++r) {
      const int q = q0 + 4 * g + r;
      Qbase[(size_t)q * 64 + h] = f2bf((accQ[t][r] + bqv) * 0.125f);
      Kbase[(size_t)q * 64 + h] = f2bf(accK[t][r] + bkv);
      const int hv = 16 * t + 4 * g + r;
      Vbase[(size_t)hv * 4096 + (q0 + l15)] = f2bf(accV[t][r] + bv[hv]);
    }
  }
}

// ---------------- flash attention ----------------
// grid 256 = 4 batches * 64 q-tiles; 4 waves * 16 q-rows each; KBLK=64
__global__ __launch_bounds__(256) void flash_kernel(
    const unsigned short* __restrict__ Qb, const unsigned short* __restrict__ Kb,
    const unsigned short* __restrict__ VT, float* __restrict__ out)
{
  __shared__ __align__(16) unsigned short P_lds[4][16][72];
  const int tid = threadIdx.x;
  const int lane = tid & 63;
  const int w = tid >> 6;
  const int l15 = lane & 15;
  const int g = lane >> 4;
  const int b = blockIdx.x >> 6;
  const int qt = blockIdx.x & 63;
  const int q0 = qt * 64 + w * 16;

  const unsigned short* Qp = Qb + (size_t)b * 4096 * 64;
  const unsigned short* Kp = Kb + (size_t)b * 4096 * 64;
  const unsigned short* Vp = VT + (size_t)b * 64 * 4096;

  // hoisted Q B-frags (S^T = K * Q^T): lane reads Q[q0+l15][d0..d0+7]
  const bf16x8 qf0 = *(const bf16x8*)(Qp + (size_t)(q0 + l15) * 64 + 8 * g);
  const bf16x8 qf1 = *(const bf16x8*)(Qp + (size_t)(q0 + l15) * 64 + 32 + 8 * g);

  f32x4 O[4];
  const f32x4 zero = {0.f, 0.f, 0.f, 0.f};
#pragma unroll
  for (int i = 0; i < 4; ++i) O[i] = zero;
  float m = -INFINITY, lsum = 0.f;
  unsigned short* Pw = &P_lds[w][0][0];

  for (int kt = 0; kt < 64; ++kt) {
    const unsigned short* Kt = Kp + (size_t)kt * 64 * 64;
    const unsigned short* Vt = Vp + (size_t)kt * 64;
    // K A-frags: lane reads K[kt*64+16t+l15][d0..d0+7]
    bf16x8 kf[8];
#pragma unroll
    for (int t = 0; t < 4; ++t) {
      kf[2 * t]     = *(const bf16x8*)(Kt + (size_t)(16 * t + l15) * 64 + 8 * g);
      kf[2 * t + 1] = *(const bf16x8*)(Kt + (size_t)(16 * t + l15) * 64 + 32 + 8 * g);
    }
    // V^T B-frags issued early (independent of S) to hide L2 latency under QK+softmax
    bf16x8 vf[8];
#pragma unroll
    for (int nt = 0; nt < 4; ++nt) {
      vf[2 * nt]     = *(const bf16x8*)(Vt + (size_t)(16 * nt + l15) * 4096 + 8 * g);
      vf[2 * nt + 1] = *(const bf16x8*)(Vt + (size_t)(16 * nt + l15) * 4096 + 32 + 8 * g);
    }
    // S^T tiles: row = key-within-tile (4g+r), col = q (l15)
    f32x4 S[4];
#pragma unroll
    for (int t = 0; t < 4; ++t) {
      S[t] = zero;
      S[t] = MFMA16(kf[2 * t], qf0, S[t]);
      S[t] = MFMA16(kf[2 * t + 1], qf1, S[t]);
    }
    // online softmax over this 64-key strip (per q = l15)
    float mt = S[0][0];
#pragma unroll
    for (int t = 0; t < 4; ++t)
#pragma unroll
      for (int r = 0; r < 4; ++r) mt = fmaxf(mt, S[t][r]);
    mt = fmaxf(mt, __shfl_xor(mt, 16));
    mt = fmaxf(mt, __shfl_xor(mt, 32));
    const float mnew = fmaxf(m, mt);
    const float alpha = __expf(m - mnew);  // first iter: expf(-inf)=0
    m = mnew;
    float ps = 0.f;
    unsigned int pp[8];
#pragma unroll
    for (int t = 0; t < 4; ++t) {
      const float p0 = __expf(S[t][0] - mnew);
      const float p1 = __expf(S[t][1] - mnew);
      const float p2 = __expf(S[t][2] - mnew);
      const float p3 = __expf(S[t][3] - mnew);
      ps += (p0 + p1) + (p2 + p3);
      pp[2 * t]     = (unsigned)f2bf(p0) | ((unsigned)f2bf(p1) << 16);
      pp[2 * t + 1] = (unsigned)f2bf(p2) | ((unsigned)f2bf(p3) << 16);
    }
    ps += __shfl_xor(ps, 16);
    ps += __shfl_xor(ps, 32);
    lsum = lsum * alpha + ps;
    // P -> wave-private LDS: row q=l15, cols k=16t+4g..+3 (b64 writes, 8B aligned)
#pragma unroll
    for (int t = 0; t < 4; ++t) {
      const unsigned long long pk =
          (unsigned long long)pp[2 * t] | ((unsigned long long)pp[2 * t + 1] << 32);
      *(unsigned long long*)(Pw + l15 * 72 + 16 * t + 4 * g) = pk;
    }
    // rescale O rows (row q-within-wave = 4g+r; alpha keyed by q=l15 -> shfl broadcast)
#pragma unroll
    for (int r = 0; r < 4; ++r) {
      const float ar = __shfl(alpha, 4 * g + r);
      O[0][r] *= ar; O[1][r] *= ar; O[2][r] *= ar; O[3][r] *= ar;
    }
    // PV: A = P from LDS (b128, 16B aligned), B = V^T frags
#pragma unroll
    for (int s = 0; s < 2; ++s) {
      const bf16x8 pa = *(const bf16x8*)(Pw + l15 * 72 + 32 * s + 8 * g);
#pragma unroll
      for (int nt = 0; nt < 4; ++nt)
        O[nt] = MFMA16(pa, vf[2 * nt + s], O[nt]);
    }
  }
  // epilogue: divide by l (per output row), store fp32
  float lr[4];
#pragma unroll
  for (int r = 0; r < 4; ++r) lr[r] = __shfl(lsum, 4 * g + r);
  float* ob = out + ((size_t)b * 4096 + q0) * 64;
#pragma unroll
  for (int nt = 0; nt < 4; ++nt) {
    const int h = 16 * nt + l15;
#pragma unroll
    for (int r = 0; r < 4; ++r)
      ob[(size_t)(4 * g + r) * 64 + h] = O[nt][r] / lr[r];
  }
}

extern "C" void kernel_launch(void* const* d_in, const int* in_sizes, int n_in,
                              void* d_out, int out_size, void* d_ws, size_t ws_size,
                              hipStream_t stream) {
  const float* x  = (const float*)d_in[0];
  const float* Wq = (const float*)d_in[1];
  const float* bq = (const float*)d_in[2];
  const float* Wk = (const float*)d_in[3];
  const float* bk = (const float*)d_in[4];
  const float* Wv = (const float*)d_in[5];
  const float* bv = (const float*)d_in[6];

  char* ws = (char*)d_ws;
  unsigned short* WT = (unsigned short*)ws;                              // 384 KB
  unsigned short* Qb = (unsigned short*)(ws + (512u << 10));             // 2 MB
  unsigned short* Kb = (unsigned short*)(ws + (512u << 10) + (2u << 20));// 2 MB
  unsigned short* VT = (unsigned short*)(ws + (512u << 10) + (4u << 20));// 2 MB
  float* out = (float*)d_out;

  hipLaunchKernelGGL(wt_kernel,    dim3(192), dim3(256), 0, stream, Wq, Wk, Wv, WT);
  hipLaunchKernelGGL(proj_kernel,  dim3(256), dim3(256), 0, stream, x, WT, bq, bk, bv, Qb, Kb, VT);
  hipLaunchKernelGGL(flash_kernel, dim3(256), dim3(256), 0, stream, Qb, Kb, VT, out);
}

// Round 2
// 189.384 us; speedup vs baseline: 1.0003x; 1.0003x over previous
//
#include <hip/hip_runtime.h>

typedef __bf16 bf16x8 __attribute__((ext_vector_type(8)));
typedef float f32x4 __attribute__((ext_vector_type(4)));
typedef unsigned short u16x8 __attribute__((ext_vector_type(8)));

union FragU { u16x8 u; bf16x8 b; };

__device__ __forceinline__ unsigned short f2bf(float f) {
  unsigned int u = __float_as_uint(f);
  u += 0x7FFFu + ((u >> 16) & 1u);
  return (unsigned short)(u >> 16);
}

#define MFMA16(a, b, c) __builtin_amdgcn_mfma_f32_16x16x32_bf16((a), (b), (c), 0, 0, 0)

// 0.125 (1/sqrt(64)) * log2(e): softmax done in base-2
#define QSCALE 0.18033688011112042f

// ---------------- W transpose: W[1024][64] f32 -> WT[3][64][1024] bf16 ----------------
__global__ __launch_bounds__(256) void wt_kernel(
    const float* __restrict__ Wq, const float* __restrict__ Wk, const float* __restrict__ Wv,
    unsigned short* __restrict__ WT)
{
  const int h = blockIdx.x & 63;
  const int mtx = blockIdx.x >> 6;  // 0..2
  const float* W = (mtx == 0) ? Wq : ((mtx == 1) ? Wk : Wv);
  for (int d = threadIdx.x; d < 1024; d += 256)
    WT[(size_t)(mtx * 64 + h) * 1024 + d] = f2bf(W[(size_t)d * 64 + h]);
}

// ---------------- QKV projection, 3-way matrix split ----------------
// grid 768 = 3 matrices x 256 row-blocks; block 256 thr = 4 waves x 16 rows
// Q[b][q][64] bf16 (pre-scaled by QSCALE), K[b][k][64] bf16, VT[b][h][4096] bf16
__global__ __launch_bounds__(256) void proj_kernel(
    const float* __restrict__ x, const unsigned short* __restrict__ WT,
    const float* __restrict__ bq, const float* __restrict__ bk, const float* __restrict__ bv,
    unsigned short* __restrict__ Qb, unsigned short* __restrict__ Kb,
    unsigned short* __restrict__ VT)
{
  const int mtx = blockIdx.x >> 8;        // 0=Q 1=K 2=V
  const int rowblk = blockIdx.x & 255;
  const int tid = threadIdx.x;
  const int lane = tid & 63;
  const int wid = tid >> 6;
  const int l15 = lane & 15;
  const int g = lane >> 4;
  const int row0 = rowblk * 64 + wid * 16;

  f32x4 acc[4];
  const f32x4 zero = {0.f, 0.f, 0.f, 0.f};
#pragma unroll
  for (int i = 0; i < 4; ++i) acc[i] = zero;

  const float* xrow = x + (size_t)(row0 + l15) * 1024;
  const unsigned short* Wm = WT + (size_t)mtx * 64 * 1024;

  for (int c = 0; c < 32; ++c) {
    const int d0 = 32 * c + 8 * g;
    f32x4 x0 = *(const f32x4*)(xrow + d0);
    f32x4 x1 = *(const f32x4*)(xrow + d0 + 4);
    FragU xf;
#pragma unroll
    for (int i = 0; i < 4; ++i) { xf.u[i] = f2bf(x0[i]); xf.u[4 + i] = f2bf(x1[i]); }
    bf16x8 wf[4];
#pragma unroll
    for (int t = 0; t < 4; ++t)
      wf[t] = *(const bf16x8*)(Wm + (size_t)(16 * t + l15) * 1024 + d0);
    if (mtx == 2) {
#pragma unroll
      for (int t = 0; t < 4; ++t) acc[t] = MFMA16(wf[t], xf.b, acc[t]);  // C[h][row] = V^T
    } else {
#pragma unroll
      for (int t = 0; t < 4; ++t) acc[t] = MFMA16(xf.b, wf[t], acc[t]);  // C[row][h]
    }
  }

  const int b = row0 >> 12;
  const int q0 = row0 & 4095;
  if (mtx == 0) {
    unsigned short* Qbase = Qb + (size_t)b * 4096 * 64;
#pragma unroll
    for (int t = 0; t < 4; ++t) {
      const int h = 16 * t + l15;
      const float bqv = bq[h];
#pragma unroll
      for (int r = 0; r < 4; ++r)
        Qbase[(size_t)(q0 + 4 * g + r) * 64 + h] = f2bf((acc[t][r] + bqv) * QSCALE);
    }
  } else if (mtx == 1) {
    unsigned short* Kbase = Kb + (size_t)b * 4096 * 64;
#pragma unroll
    for (int t = 0; t < 4; ++t) {
      const int h = 16 * t + l15;
      const float bkv = bk[h];
#pragma unroll
      for (int r = 0; r < 4; ++r)
        Kbase[(size_t)(q0 + 4 * g + r) * 64 + h] = f2bf(acc[t][r] + bkv);
    }
  } else {
    unsigned short* Vbase = VT + (size_t)b * 64 * 4096;
#pragma unroll
    for (int t = 0; t < 4; ++t) {
#pragma unroll
      for (int r = 0; r < 4; ++r) {
        const int hv = 16 * t + 4 * g + r;
        Vbase[(size_t)hv * 4096 + (q0 + l15)] = f2bf(acc[t][r] + bv[hv]);
      }
    }
  }
}

// ---------------- flash attention, k-split in block ----------------
// grid 512 = 4 batches * 128 q-blocks(32 rows); block 512 thr = 8 waves
// wave w: q-group qg=w>>2 (16 rows), k-split ks=w&3 (tiles ks,ks+4,...,ks+60)
// epilogue: in-LDS combine of 4 partials per q-group
__global__ __launch_bounds__(512, 4) void flash_kernel(
    const unsigned short* __restrict__ Qb, const unsigned short* __restrict__ Kb,
    const unsigned short* __restrict__ VT, float* __restrict__ out)
{
  __shared__ __align__(16) unsigned char lds[36864];  // P[8][16][72]u16 | O[8][16][68]f32 + ml[8][16][2]f32
  const int tid = threadIdx.x;
  const int lane = tid & 63;
  const int w = tid >> 6;
  const int l15 = lane & 15;
  const int g = lane >> 4;
  const int ks = w & 3;
  const int qg = w >> 2;
  const int b = blockIdx.x >> 7;
  const int qt = blockIdx.x & 127;
  const int q0 = qt * 32 + qg * 16;

  const unsigned short* Qp = Qb + (size_t)b * 4096 * 64;
  const unsigned short* Kp = Kb + (size_t)b * 4096 * 64;
  const unsigned short* Vp = VT + (size_t)b * 64 * 4096;

  // hoisted Q B-frags (S^T = K * Q^T): lane reads Q[q0+l15][d0..d0+7]
  const bf16x8 qf0 = *(const bf16x8*)(Qp + (size_t)(q0 + l15) * 64 + 8 * g);
  const bf16x8 qf1 = *(const bf16x8*)(Qp + (size_t)(q0 + l15) * 64 + 32 + 8 * g);

  f32x4 O[4];
  const f32x4 zero = {0.f, 0.f, 0.f, 0.f};
#pragma unroll
  for (int i = 0; i < 4; ++i) O[i] = zero;
  float m = -INFINITY, lsum = 0.f;
  unsigned short* Pw = (unsigned short*)lds + w * 16 * 72;

  for (int kt = ks; kt < 64; kt += 4) {
    const unsigned short* Kt = Kp + (size_t)kt * 64 * 64;
    const unsigned short* Vt = Vp + (size_t)kt * 64;
    bf16x8 kf[8];
#pragma unroll
    for (int t = 0; t < 4; ++t) {
      kf[2 * t]     = *(const bf16x8*)(Kt + (size_t)(16 * t + l15) * 64 + 8 * g);
      kf[2 * t + 1] = *(const bf16x8*)(Kt + (size_t)(16 * t + l15) * 64 + 32 + 8 * g);
    }
    // V^T B-frags issued early (independent of S) to hide latency under QK+softmax
    bf16x8 vf[8];
#pragma unroll
    for (int nt = 0; nt < 4; ++nt) {
      vf[2 * nt]     = *(const bf16x8*)(Vt + (size_t)(16 * nt + l15) * 4096 + 8 * g);
      vf[2 * nt + 1] = *(const bf16x8*)(Vt + (size_t)(16 * nt + l15) * 4096 + 32 + 8 * g);
    }
    // S^T tiles: row = key-within-tile (4g+r), col = q (l15); base-2 logits
    f32x4 S[4];
#pragma unroll
    for (int t = 0; t < 4; ++t) {
      S[t] = zero;
      S[t] = MFMA16(kf[2 * t], qf0, S[t]);
      S[t] = MFMA16(kf[2 * t + 1], qf1, S[t]);
    }
    // online softmax (base 2) over this 64-key strip (per q = l15)
    float mt = fmaxf(fmaxf(S[0][0], S[0][1]), fmaxf(S[0][2], S[0][3]));
#pragma unroll
    for (int t = 1; t < 4; ++t)
#pragma unroll
      for (int r = 0; r < 4; ++r) mt = fmaxf(mt, S[t][r]);
    mt = fmaxf(mt, __shfl_xor(mt, 16));
    mt = fmaxf(mt, __shfl_xor(mt, 32));
    // defer-max: only rescale when max grew by > 8 (P bounded by 2^8)
    if (!__all(mt <= m + 8.0f)) {
      const float mnew = fmaxf(m, mt);
      const float alpha = __builtin_amdgcn_exp2f(m - mnew);  // first iter: 0
      m = mnew;
      lsum *= alpha;
#pragma unroll
      for (int r = 0; r < 4; ++r) {
        const float ar = __shfl(alpha, 4 * g + r);
        O[0][r] *= ar; O[1][r] *= ar; O[2][r] *= ar; O[3][r] *= ar;
      }
    }
    float ps = 0.f;
    unsigned int pp[8];
#pragma unroll
    for (int t = 0; t < 4; ++t) {
      const float p0 = __builtin_amdgcn_exp2f(S[t][0] - m);
      const float p1 = __builtin_amdgcn_exp2f(S[t][1] - m);
      const float p2 = __builtin_amdgcn_exp2f(S[t][2] - m);
      const float p3 = __builtin_amdgcn_exp2f(S[t][3] - m);
      ps += (p0 + p1) + (p2 + p3);
      pp[2 * t]     = (unsigned)f2bf(p0) | ((unsigned)f2bf(p1) << 16);
      pp[2 * t + 1] = (unsigned)f2bf(p2) | ((unsigned)f2bf(p3) << 16);
    }
    ps += __shfl_xor(ps, 16);
    ps += __shfl_xor(ps, 32);
    lsum += ps;
    // P -> wave-private LDS: row q=l15, cols k=16t+4g..+3
#pragma unroll
    for (int t = 0; t < 4; ++t) {
      const unsigned long long pk =
          (unsigned long long)pp[2 * t] | ((unsigned long long)pp[2 * t + 1] << 32);
      *(unsigned long long*)(Pw + l15 * 72 + 16 * t + 4 * g) = pk;
    }
    // PV: A = P from LDS (b128), B = V^T frags
#pragma unroll
    for (int s = 0; s < 2; ++s) {
      const bf16x8 pa = *(const bf16x8*)(Pw + l15 * 72 + 32 * s + 8 * g);
#pragma unroll
      for (int nt = 0; nt < 4; ++nt)
        O[nt] = MFMA16(pa, vf[2 * nt + s], O[nt]);
    }
  }

  // ---- in-LDS combine of the 4 k-split partials per q-group ----
  __syncthreads();  // everyone done with P region
  float* O_l = (float*)lds;                 // [8][16][68]
  float* mlp = (float*)(lds + 34816);       // [8][16][2]
#pragma unroll
  for (int nt = 0; nt < 4; ++nt)
#pragma unroll
    for (int r = 0; r < 4; ++r)
      O_l[(w * 16 + 4 * g + r) * 68 + 16 * nt + l15] = O[nt][r];
  if (g == 0) { mlp[(w * 16 + l15) * 2] = m; mlp[(w * 16 + l15) * 2 + 1] = lsum; }
  __syncthreads();

  // thread t: row q = t>>4 (0..31), cols h0..h0+3
  const int q = tid >> 4;
  const int h0 = (tid & 15) * 4;
  const int qg2 = q >> 4, qr = q & 15;
  float M = -INFINITY;
#pragma unroll
  for (int s = 0; s < 4; ++s) M = fmaxf(M, mlp[((qg2 * 4 + s) * 16 + qr) * 2]);
  float L = 0.f;
  f32x4 accv = zero;
#pragma unroll
  for (int s = 0; s < 4; ++s) {
    const int ww = qg2 * 4 + s;
    const float wgt = __builtin_amdgcn_exp2f(mlp[(ww * 16 + qr) * 2] - M);
    L += wgt * mlp[(ww * 16 + qr) * 2 + 1];
    const f32x4 o = *(const f32x4*)&O_l[(ww * 16 + qr) * 68 + h0];
#pragma unroll
    for (int i = 0; i < 4; ++i) accv[i] += wgt * o[i];
  }
  const float inv = 1.0f / L;
  float* ob = out + ((size_t)b * 4096 + qt * 32 + q) * 64 + h0;
  f32x4 res = {accv[0] * inv, accv[1] * inv, accv[2] * inv, accv[3] * inv};
  *(f32x4*)ob = res;
}

extern "C" void kernel_launch(void* const* d_in, const int* in_sizes, int n_in,
                              void* d_out, int out_size, void* d_ws, size_t ws_size,
                              hipStream_t stream) {
  const float* x  = (const float*)d_in[0];
  const float* Wq = (const float*)d_in[1];
  const float* bq = (const float*)d_in[2];
  const float* Wk = (const float*)d_in[3];
  const float* bk = (const float*)d_in[4];
  const float* Wv = (const float*)d_in[5];
  const float* bv = (const float*)d_in[6];

  char* ws = (char*)d_ws;
  unsigned short* WT = (unsigned short*)ws;                              // 384 KB
  unsigned short* Qb = (unsigned short*)(ws + (512u << 10));             // 2 MB
  unsigned short* Kb = (unsigned short*)(ws + (512u << 10) + (2u << 20));// 2 MB
  unsigned short* VT = (unsigned short*)(ws + (512u << 10) + (4u << 20));// 2 MB
  float* out = (float*)d_out;

  hipLaunchKernelGGL(wt_kernel,    dim3(192), dim3(256), 0, stream, Wq, Wk, Wv, WT);
  hipLaunchKernelGGL(proj_kernel,  dim3(768), dim3(256), 0, stream, x, WT, bq, bk, bv, Qb, Kb, VT);
  hipLaunchKernelGGL(flash_kernel, dim3(512), dim3(512), 0, stream, Qb, Kb, VT, out);
}

// Round 3
// 71.352 us; speedup vs baseline: 2.6552x; 2.6542x over previous
//
#include <hip/hip_runtime.h>

typedef __bf16 bf16x8 __attribute__((ext_vector_type(8)));
typedef __bf16 bf16x4 __attribute__((ext_vector_type(4)));
typedef float f32x4 __attribute__((ext_vector_type(4)));
typedef unsigned short u16x8 __attribute__((ext_vector_type(8)));

union FragU { u16x8 u; bf16x8 b; };
union PackU { bf16x4 v; unsigned long long q; };

__device__ __forceinline__ unsigned short bfbits(float f) {
  __bf16 h = (__bf16)f;
  union { __bf16 h; unsigned short s; } cv; cv.h = h;
  return cv.s;
}

#define MFMA16(a, b, c) __builtin_amdgcn_mfma_f32_16x16x32_bf16((a), (b), (c), 0, 0, 0)

// 0.125 (1/sqrt(64)) * log2(e): softmax done in base-2
#define QSCALE 0.18033688011112042f

// ---------------- W -> fragment-order bf16: WF[m][c][t][lane][8] ----------------
// value(m,c,t,lane=g*16+l15,e) = W_m[32c + 8g + e][16t + l15]
__global__ __launch_bounds__(256) void wt_kernel(
    const float* __restrict__ Wq, const float* __restrict__ Wk, const float* __restrict__ Wv,
    unsigned short* __restrict__ WF)
{
  const int m = blockIdx.x >> 5;         // 0..2
  const int c = blockIdx.x & 31;         // 0..31
  const float* W = (m == 0) ? Wq : ((m == 1) ? Wk : Wv);
  const int t = threadIdx.x >> 6;
  const int lane = threadIdx.x & 63;
  const int l15 = lane & 15;
  const int g = lane >> 4;
  unsigned short* dst = WF + ((((size_t)m * 32 + c) * 4 + t) * 64 + lane) * 8;
#pragma unroll
  for (int e = 0; e < 8; ++e)
    dst[e] = bfbits(W[(size_t)(32 * c + 8 * g + e) * 64 + (16 * t + l15)]);
}

// ---------------- fused QKV projection, software-pipelined ----------------
// grid 256 blocks x 256 thr (4 waves x 16 rows). x read ONCE.
// Q[b][q][64] bf16 (pre-scaled), KF/VF in per-tile fragment order.
__global__ __launch_bounds__(256, 1) void proj_kernel(
    const float* __restrict__ x, const unsigned short* __restrict__ WF,
    const float* __restrict__ bq, const float* __restrict__ bk, const float* __restrict__ bv,
    unsigned short* __restrict__ Qb, unsigned short* __restrict__ KF,
    unsigned short* __restrict__ VF)
{
  const int tid = threadIdx.x;
  const int lane = tid & 63;
  const int wid = tid >> 6;
  const int l15 = lane & 15;
  const int g = lane >> 4;
  const int row0 = blockIdx.x * 64 + wid * 16;

  f32x4 accQ[4], accK[4], accV[4];
  const f32x4 zero = {0.f, 0.f, 0.f, 0.f};
#pragma unroll
  for (int i = 0; i < 4; ++i) { accQ[i] = zero; accK[i] = zero; accV[i] = zero; }

  const float* xrow = x + (size_t)(row0 + l15) * 1024;

  f32x4 xx0[4], xx1[4];
  bf16x8 wq[2][4], wk[2][4], wv[2][4];

#define PLDX(XB, C) { xx0[XB] = *(const f32x4*)(xrow + 32 * (C) + 8 * g); \
                      xx1[XB] = *(const f32x4*)(xrow + 32 * (C) + 8 * g + 4); }
#define PLDW(WS, C) { _Pragma("unroll") for (int t = 0; t < 4; ++t) { \
    wq[WS][t] = *(const bf16x8*)(WF + ((((size_t)0 * 32 + (C)) * 4 + t) * 64 + lane) * 8); \
    wk[WS][t] = *(const bf16x8*)(WF + ((((size_t)1 * 32 + (C)) * 4 + t) * 64 + lane) * 8); \
    wv[WS][t] = *(const bf16x8*)(WF + ((((size_t)2 * 32 + (C)) * 4 + t) * 64 + lane) * 8); } }
#define PHALF(XB, WS, CXN, CWN) { \
    FragU xf; \
    _Pragma("unroll") for (int i = 0; i < 4; ++i) { \
      xf.b[i] = (__bf16)xx0[XB][i]; xf.b[4 + i] = (__bf16)xx1[XB][i]; } \
    if ((CXN) < 32) PLDX(XB, CXN); \
    _Pragma("unroll") for (int t = 0; t < 4; ++t) { \
      accQ[t] = MFMA16(xf.b, wq[WS][t], accQ[t]); \
      accK[t] = MFMA16(xf.b, wk[WS][t], accK[t]); \
      accV[t] = MFMA16(wv[WS][t], xf.b, accV[t]); } \
    if ((CWN) < 32) PLDW(WS, CWN); }

  PLDX(0, 0) PLDX(1, 1) PLDX(2, 2) PLDX(3, 3)
  PLDW(0, 0) PLDW(1, 1)

#pragma unroll 1
  for (int c = 0; c < 32; c += 4) {
    PHALF(0, 0, c + 4, c + 2)
    PHALF(1, 1, c + 5, c + 3)
    PHALF(2, 0, c + 6, c + 4)
    PHALF(3, 1, c + 7, c + 5)
  }

  const int b = blockIdx.x >> 6;
  const int kt = blockIdx.x & 63;
  const int q0 = row0 & 4095;
  // Q row-major (read once per flash wave)
  unsigned short* Qbase = Qb + (size_t)b * 4096 * 64;
#pragma unroll
  for (int t = 0; t < 4; ++t) {
    const int h = 16 * t + l15;
    const float bqv = bq[h];
#pragma unroll
    for (int r = 0; r < 4; ++r)
      Qbase[(size_t)(q0 + 4 * g + r) * 64 + h] = bfbits((accQ[t][r] + bqv) * QSCALE);
  }
  // K fragment order: KFb[((wid*2 + (t>>1))*64 + (t&1)*32 + (l15>>3)*16 + 4g+r)*8 + (l15&7)]
  unsigned short* KFb = KF + ((size_t)b * 64 + kt) * 4096;
  unsigned short* VFb = VF + ((size_t)b * 64 + kt) * 4096;
#pragma unroll
  for (int t = 0; t < 4; ++t) {
    const int h = 16 * t + l15;
    const float bkv = bk[h];
#pragma unroll
    for (int r = 0; r < 4; ++r) {
      KFb[(size_t)((wid * 2 + (t >> 1)) * 64 + (t & 1) * 32 + (l15 >> 3) * 16 + 4 * g + r) * 8 +
          (l15 & 7)] = bfbits(accK[t][r] + bkv);
      const int hv = 16 * t + 4 * g + r;
      VFb[(size_t)((t * 2 + (wid >> 1)) * 64 + (wid & 1) * 32 + (l15 >> 3) * 16 + 4 * g + r) * 8 +
          (l15 & 7)] = bfbits(accV[t][r] + bv[hv]);
    }
  }
}

// ---------------- flash attention, k-split in block, XCD-local batches ----------------
// grid 512; swizzle: xcd = bid&7 -> batch xcd>>1; block 512 thr = 8 waves
// wave w: q-group qg=w>>2 (16 rows), k-split ks=w&3; in-LDS combine at end
__global__ __launch_bounds__(512, 4) void flash_kernel(
    const unsigned short* __restrict__ Qb, const unsigned short* __restrict__ KF,
    const unsigned short* __restrict__ VF, float* __restrict__ out)
{
  __shared__ __align__(16) unsigned char lds[36864];
  const int tid = threadIdx.x;
  const int lane = tid & 63;
  const int w = tid >> 6;
  const int l15 = lane & 15;
  const int g = lane >> 4;
  const int ks = w & 3;
  // XCD swizzle: each XCD pair owns one batch
  const int bid = blockIdx.x;
  const int xcd = bid & 7;
  const int b = xcd >> 1;
  const int qt = (bid >> 3) * 2 + (xcd & 1);
  const int q0 = qt * 32 + (w >> 2) * 16;

  const unsigned short* Qp = Qb + (size_t)b * 4096 * 64;
  const unsigned short* KFb = KF + (size_t)b * 262144;
  const unsigned short* VFb = VF + (size_t)b * 262144;

  const bf16x8 qf0 = *(const bf16x8*)(Qp + (size_t)(q0 + l15) * 64 + 8 * g);
  const bf16x8 qf1 = *(const bf16x8*)(Qp + (size_t)(q0 + l15) * 64 + 32 + 8 * g);

  f32x4 O[4];
  const f32x4 zero = {0.f, 0.f, 0.f, 0.f};
#pragma unroll
  for (int i = 0; i < 4; ++i) O[i] = zero;
  float m = -INFINITY, lsum = 0.f;
  unsigned short* Pw = (unsigned short*)lds + w * 16 * 72;

#pragma unroll 1
  for (int kt = ks; kt < 64; kt += 4) {
    const unsigned short* Kt = KFb + kt * 4096;
    const unsigned short* Vt = VFb + kt * 4096;
    // fragment-contiguous loads: 64 lanes x 16B consecutive per frag
    bf16x8 kf[8], vf[8];
#pragma unroll
    for (int j = 0; j < 8; ++j) kf[j] = *(const bf16x8*)(Kt + (j * 64 + lane) * 8);
#pragma unroll
    for (int j = 0; j < 8; ++j) vf[j] = *(const bf16x8*)(Vt + (j * 64 + lane) * 8);
    // S^T tiles: row = key-within-tile (4g+r), col = q (l15); base-2 logits
    f32x4 S[4];
#pragma unroll
    for (int t = 0; t < 4; ++t) {
      S[t] = zero;
      S[t] = MFMA16(kf[2 * t], qf0, S[t]);
      S[t] = MFMA16(kf[2 * t + 1], qf1, S[t]);
    }
    float mt = fmaxf(fmaxf(S[0][0], S[0][1]), fmaxf(S[0][2], S[0][3]));
#pragma unroll
    for (int t = 1; t < 4; ++t)
#pragma unroll
      for (int r = 0; r < 4; ++r) mt = fmaxf(mt, S[t][r]);
    mt = fmaxf(mt, __shfl_xor(mt, 16));
    mt = fmaxf(mt, __shfl_xor(mt, 32));
    // defer-max: only rescale when max grew by > 8 (P bounded by 2^8)
    if (!__all(mt <= m + 8.0f)) {
      const float mnew = fmaxf(m, mt);
      const float alpha = __builtin_amdgcn_exp2f(m - mnew);
      m = mnew;
      lsum *= alpha;
#pragma unroll
      for (int r = 0; r < 4; ++r) {
        const float ar = __shfl(alpha, 4 * g + r);
        O[0][r] *= ar; O[1][r] *= ar; O[2][r] *= ar; O[3][r] *= ar;
      }
    }
    float ps = 0.f;
#pragma unroll
    for (int t = 0; t < 4; ++t) {
      const float p0 = __builtin_amdgcn_exp2f(S[t][0] - m);
      const float p1 = __builtin_amdgcn_exp2f(S[t][1] - m);
      const float p2 = __builtin_amdgcn_exp2f(S[t][2] - m);
      const float p3 = __builtin_amdgcn_exp2f(S[t][3] - m);
      ps += (p0 + p1) + (p2 + p3);
      PackU pk;
      pk.v[0] = (__bf16)p0; pk.v[1] = (__bf16)p1;
      pk.v[2] = (__bf16)p2; pk.v[3] = (__bf16)p3;
      *(unsigned long long*)(Pw + l15 * 72 + 16 * t + 4 * g) = pk.q;
    }
    ps += __shfl_xor(ps, 16);
    ps += __shfl_xor(ps, 32);
    lsum += ps;
    // PV: A = P from LDS (b128), B = V^T frags
#pragma unroll
    for (int s = 0; s < 2; ++s) {
      const bf16x8 pa = *(const bf16x8*)(Pw + l15 * 72 + 32 * s + 8 * g);
#pragma unroll
      for (int nt = 0; nt < 4; ++nt)
        O[nt] = MFMA16(pa, vf[2 * nt + s], O[nt]);
    }
  }

  // ---- in-LDS combine of the 4 k-split partials per q-group ----
  __syncthreads();
  float* O_l = (float*)lds;                 // [8][16][68]
  float* mlp = (float*)(lds + 34816);       // [8][16][2]
#pragma unroll
  for (int nt = 0; nt < 4; ++nt)
#pragma unroll
    for (int r = 0; r < 4; ++r)
      O_l[(w * 16 + 4 * g + r) * 68 + 16 * nt + l15] = O[nt][r];
  if (g == 0) { mlp[(w * 16 + l15) * 2] = m; mlp[(w * 16 + l15) * 2 + 1] = lsum; }
  __syncthreads();

  const int q = tid >> 4;
  const int h0 = (tid & 15) * 4;
  const int qg2 = q >> 4, qr = q & 15;
  float M = -INFINITY;
#pragma unroll
  for (int s = 0; s < 4; ++s) M = fmaxf(M, mlp[((qg2 * 4 + s) * 16 + qr) * 2]);
  float L = 0.f;
  f32x4 accv = zero;
#pragma unroll
  for (int s = 0; s < 4; ++s) {
    const int ww = qg2 * 4 + s;
    const float wgt = __builtin_amdgcn_exp2f(mlp[(ww * 16 + qr) * 2] - M);
    L += wgt * mlp[(ww * 16 + qr) * 2 + 1];
    const f32x4 o = *(const f32x4*)&O_l[(ww * 16 + qr) * 68 + h0];
#pragma unroll
    for (int i = 0; i < 4; ++i) accv[i] += wgt * o[i];
  }
  const float inv = 1.0f / L;
  float* ob = out + ((size_t)b * 4096 + qt * 32 + q) * 64 + h0;
  f32x4 res = {accv[0] * inv, accv[1] * inv, accv[2] * inv, accv[3] * inv};
  *(f32x4*)ob = res;
}

extern "C" void kernel_launch(void* const* d_in, const int* in_sizes, int n_in,
                              void* d_out, int out_size, void* d_ws, size_t ws_size,
                              hipStream_t stream) {
  const float* x  = (const float*)d_in[0];
  const float* Wq = (const float*)d_in[1];
  const float* bq = (const float*)d_in[2];
  const float* Wk = (const float*)d_in[3];
  const float* bk = (const float*)d_in[4];
  const float* Wv = (const float*)d_in[5];
  const float* bv = (const float*)d_in[6];

  char* ws = (char*)d_ws;
  unsigned short* WF = (unsigned short*)ws;                              // 384 KB
  unsigned short* Qb = (unsigned short*)(ws + (512u << 10));             // 2 MB
  unsigned short* KF = (unsigned short*)(ws + (512u << 10) + (2u << 20));// 2 MB
  unsigned short* VF = (unsigned short*)(ws + (512u << 10) + (4u << 20));// 2 MB
  float* out = (float*)d_out;

  hipLaunchKernelGGL(wt_kernel,    dim3(96),  dim3(256), 0, stream, Wq, Wk, Wv, WF);
  hipLaunchKernelGGL(proj_kernel,  dim3(256), dim3(256), 0, stream, x, WF, bq, bk, bv, Qb, KF, VF);
  hipLaunchKernelGGL(flash_kernel, dim3(512), dim3(512), 0, stream, Qb, KF, VF, out);
}

// Round 5
// 61.344 us; speedup vs baseline: 3.0883x; 1.1631x over previous
//
#include <hip/hip_runtime.h>

typedef __bf16 bf16x8 __attribute__((ext_vector_type(8)));
typedef __bf16 bf16x4 __attribute__((ext_vector_type(4)));
typedef float f32x4 __attribute__((ext_vector_type(4)));
typedef unsigned short u16x8 __attribute__((ext_vector_type(8)));

union FragU { u16x8 u; bf16x8 b; };
union PackU { bf16x4 v; unsigned long long q; };

__device__ __forceinline__ unsigned short bfbits(float f) {
  __bf16 h = (__bf16)f;
  union { __bf16 h; unsigned short s; } cv; cv.h = h;
  return cv.s;
}

#define MFMA16(a, b, c) __builtin_amdgcn_mfma_f32_16x16x32_bf16((a), (b), (c), 0, 0, 0)

// 0.125 (1/sqrt(64)) * log2(e): softmax done in base-2
#define QSCALE 0.18033688011112042f

// ---------------- W -> fragment-order bf16: WF[m][c][t][lane][8] ----------------
__global__ __launch_bounds__(256) void wt_kernel(
    const float* __restrict__ Wq, const float* __restrict__ Wk, const float* __restrict__ Wv,
    unsigned short* __restrict__ WF)
{
  const int m = blockIdx.x >> 5;         // 0..2
  const int c = blockIdx.x & 31;         // 0..31
  const float* W = (m == 0) ? Wq : ((m == 1) ? Wk : Wv);
  const int t = threadIdx.x >> 6;
  const int lane = threadIdx.x & 63;
  const int l15 = lane & 15;
  const int g = lane >> 4;
  unsigned short* dst = WF + ((((size_t)m * 32 + c) * 4 + t) * 64 + lane) * 8;
#pragma unroll
  for (int e = 0; e < 8; ++e)
    dst[e] = bfbits(W[(size_t)(32 * c + 8 * g + e) * 64 + (16 * t + l15)]);
}

// ---------------- fused QKV projection, software-pipelined (R3-proven) ----------------
// grid 256 blocks x 256 thr (4 waves x 16 rows). x read ONCE.
__global__ __launch_bounds__(256, 1) void proj_kernel(
    const float* __restrict__ x, const unsigned short* __restrict__ WF,
    const float* __restrict__ bq, const float* __restrict__ bk, const float* __restrict__ bv,
    unsigned short* __restrict__ Qb, unsigned short* __restrict__ KF,
    unsigned short* __restrict__ VF)
{
  const int tid = threadIdx.x;
  const int lane = tid & 63;
  const int wid = tid >> 6;               // 0..3
  const int l15 = lane & 15;
  const int g = lane >> 4;
  const int row0 = blockIdx.x * 64 + wid * 16;

  f32x4 accQ[4], accK[4], accV[4];
  const f32x4 zero = {0.f, 0.f, 0.f, 0.f};
#pragma unroll
  for (int i = 0; i < 4; ++i) { accQ[i] = zero; accK[i] = zero; accV[i] = zero; }

  const float* xrow = x + (size_t)(row0 + l15) * 1024;

  f32x4 xx0[4], xx1[4];
  bf16x8 wq[2][4], wk[2][4], wv[2][4];

#define PLDX(XB, C) { xx0[XB] = *(const f32x4*)(xrow + 32 * (C) + 8 * g); \
                      xx1[XB] = *(const f32x4*)(xrow + 32 * (C) + 8 * g + 4); }
#define PLDW(WS, C) { _Pragma("unroll") for (int t = 0; t < 4; ++t) { \
    wq[WS][t] = *(const bf16x8*)(WF + ((((size_t)0 * 32 + (C)) * 4 + t) * 64 + lane) * 8); \
    wk[WS][t] = *(const bf16x8*)(WF + ((((size_t)1 * 32 + (C)) * 4 + t) * 64 + lane) * 8); \
    wv[WS][t] = *(const bf16x8*)(WF + ((((size_t)2 * 32 + (C)) * 4 + t) * 64 + lane) * 8); } }
#define PHALF(XB, WS, CXN, CWN) { \
    FragU xf; \
    _Pragma("unroll") for (int i = 0; i < 4; ++i) { \
      xf.b[i] = (__bf16)xx0[XB][i]; xf.b[4 + i] = (__bf16)xx1[XB][i]; } \
    if ((CXN) < 32) PLDX(XB, CXN); \
    _Pragma("unroll") for (int t = 0; t < 4; ++t) { \
      accQ[t] = MFMA16(xf.b, wq[WS][t], accQ[t]); \
      accK[t] = MFMA16(xf.b, wk[WS][t], accK[t]); \
      accV[t] = MFMA16(wv[WS][t], xf.b, accV[t]); } \
    if ((CWN) < 32) PLDW(WS, CWN); }

  PLDX(0, 0) PLDX(1, 1) PLDX(2, 2) PLDX(3, 3)
  PLDW(0, 0) PLDW(1, 1)

#pragma unroll 1
  for (int c = 0; c < 32; c += 4) {
    PHALF(0, 0, c + 4, c + 2)
    PHALF(1, 1, c + 5, c + 3)
    PHALF(2, 0, c + 6, c + 4)
    PHALF(3, 1, c + 7, c + 5)
  }

  const int b = blockIdx.x >> 6;
  const int kt = blockIdx.x & 63;
  const int q0 = row0 & 4095;
  unsigned short* Qbase = Qb + (size_t)b * 4096 * 64;
#pragma unroll
  for (int t = 0; t < 4; ++t) {
    const int h = 16 * t + l15;
    const float bqv = bq[h];
#pragma unroll
    for (int r = 0; r < 4; ++r)
      Qbase[(size_t)(q0 + 4 * g + r) * 64 + h] = bfbits((accQ[t][r] + bqv) * QSCALE);
  }
  unsigned short* KFb = KF + ((size_t)b * 64 + kt) * 4096;
  unsigned short* VFb = VF + ((size_t)b * 64 + kt) * 4096;
#pragma unroll
  for (int t = 0; t < 4; ++t) {
    const int h = 16 * t + l15;
    const float bkv = bk[h];
#pragma unroll
    for (int r = 0; r < 4; ++r) {
      KFb[(size_t)((wid * 2 + (t >> 1)) * 64 + (t & 1) * 32 + (l15 >> 3) * 16 + 4 * g + r) * 8 +
          (l15 & 7)] = bfbits(accK[t][r] + bkv);
      const int hv = 16 * t + 4 * g + r;
      VFb[(size_t)((t * 2 + (wid >> 1)) * 64 + (wid & 1) * 32 + (l15 >> 3) * 16 + 4 * g + r) * 8 +
          (l15 & 7)] = bfbits(accV[t][r] + bv[hv]);
    }
  }
}

// ---------------- flash attention: 32 q-rows/wave, k-split 4 ----------------
// grid 512 = XCD-swizzled (4 batches x 128 q-blocks of 32 rows); block 256 thr = 4 waves.
// All 4 waves share the SAME 32 q-rows; wave w sweeps tiles kt = w, w+4, ...
__global__ __launch_bounds__(256, 2) void flash_kernel(
    const unsigned short* __restrict__ Qb, const unsigned short* __restrict__ KF,
    const unsigned short* __restrict__ VF, float* __restrict__ out)
{
  __shared__ __align__(16) unsigned char lds[36864];
  const int tid = threadIdx.x;
  const int lane = tid & 63;
  const int w = tid >> 6;                 // 0..3 = k-split
  const int l15 = lane & 15;
  const int g = lane >> 4;
  const int bid = blockIdx.x;
  const int xcd = bid & 7;
  const int b = xcd >> 1;
  const int qt = (bid >> 3) * 2 + (xcd & 1);   // 0..127
  const int q0 = qt * 32;

  const unsigned short* Qp = Qb + (size_t)b * 4096 * 64;
  const unsigned short* KFb = KF + (size_t)b * 262144;
  const unsigned short* VFb = VF + (size_t)b * 262144;

  const bf16x8 qfA0 = *(const bf16x8*)(Qp + (size_t)(q0 + l15) * 64 + 8 * g);
  const bf16x8 qfA1 = *(const bf16x8*)(Qp + (size_t)(q0 + l15) * 64 + 32 + 8 * g);
  const bf16x8 qfB0 = *(const bf16x8*)(Qp + (size_t)(q0 + 16 + l15) * 64 + 8 * g);
  const bf16x8 qfB1 = *(const bf16x8*)(Qp + (size_t)(q0 + 16 + l15) * 64 + 32 + 8 * g);

  f32x4 O_A[4], O_B[4];
  const f32x4 zero = {0.f, 0.f, 0.f, 0.f};
#pragma unroll
  for (int i = 0; i < 4; ++i) { O_A[i] = zero; O_B[i] = zero; }
  float mA = -INFINITY, lA = 0.f, mB = -INFINITY, lB = 0.f;
  unsigned short* PwA = (unsigned short*)lds + (w * 2 + 0) * 1152;
  unsigned short* PwB = (unsigned short*)lds + (w * 2 + 1) * 1152;

#define SM_HALF(S, mvar, lvar, OA, PW) { \
  float mt = fmaxf(fmaxf(S[0][0], S[0][1]), fmaxf(S[0][2], S[0][3])); \
  _Pragma("unroll") for (int t = 1; t < 4; ++t) \
    _Pragma("unroll") for (int r = 0; r < 4; ++r) mt = fmaxf(mt, S[t][r]); \
  mt = fmaxf(mt, __shfl_xor(mt, 16)); \
  mt = fmaxf(mt, __shfl_xor(mt, 32)); \
  if (!__all(mt <= mvar + 8.0f)) { \
    const float mnew = fmaxf(mvar, mt); \
    const float alpha = __builtin_amdgcn_exp2f(mvar - mnew); \
    mvar = mnew; lvar *= alpha; \
    _Pragma("unroll") for (int r = 0; r < 4; ++r) { \
      const float ar = __shfl(alpha, 4 * g + r); \
      OA[0][r] *= ar; OA[1][r] *= ar; OA[2][r] *= ar; OA[3][r] *= ar; } \
  } \
  float ps = 0.f; \
  _Pragma("unroll") for (int t = 0; t < 4; ++t) { \
    const float p0 = __builtin_amdgcn_exp2f(S[t][0] - mvar); \
    const float p1 = __builtin_amdgcn_exp2f(S[t][1] - mvar); \
    const float p2 = __builtin_amdgcn_exp2f(S[t][2] - mvar); \
    const float p3 = __builtin_amdgcn_exp2f(S[t][3] - mvar); \
    ps += (p0 + p1) + (p2 + p3); \
    PackU pk_; pk_.v[0] = (__bf16)p0; pk_.v[1] = (__bf16)p1; \
    pk_.v[2] = (__bf16)p2; pk_.v[3] = (__bf16)p3; \
    *(unsigned long long*)((PW) + l15 * 72 + 16 * t + 4 * g) = pk_.q; } \
  ps += __shfl_xor(ps, 16); \
  ps += __shfl_xor(ps, 32); \
  lvar += ps; }

#pragma unroll 1
  for (int kt = w; kt < 64; kt += 4) {
    const unsigned short* Kt = KFb + kt * 4096;
    const unsigned short* Vt = VFb + kt * 4096;
    bf16x8 kf[8], vf[8];
#pragma unroll
    for (int j = 0; j < 8; ++j) kf[j] = *(const bf16x8*)(Kt + (j * 64 + lane) * 8);
#pragma unroll
    for (int j = 0; j < 8; ++j) vf[j] = *(const bf16x8*)(Vt + (j * 64 + lane) * 8);
    f32x4 S_A[4], S_B[4];
#pragma unroll
    for (int t = 0; t < 4; ++t) {
      S_A[t] = zero;
      S_A[t] = MFMA16(kf[2 * t], qfA0, S_A[t]);
      S_A[t] = MFMA16(kf[2 * t + 1], qfA1, S_A[t]);
      S_B[t] = zero;
      S_B[t] = MFMA16(kf[2 * t], qfB0, S_B[t]);
      S_B[t] = MFMA16(kf[2 * t + 1], qfB1, S_B[t]);
    }
    SM_HALF(S_A, mA, lA, O_A, PwA)
    SM_HALF(S_B, mB, lB, O_B, PwB)
#pragma unroll
    for (int s = 0; s < 2; ++s) {
      const bf16x8 paA = *(const bf16x8*)(PwA + l15 * 72 + 32 * s + 8 * g);
      const bf16x8 paB = *(const bf16x8*)(PwB + l15 * 72 + 32 * s + 8 * g);
#pragma unroll
      for (int nt = 0; nt < 4; ++nt) {
        O_A[nt] = MFMA16(paA, vf[2 * nt + s], O_A[nt]);
        O_B[nt] = MFMA16(paB, vf[2 * nt + s], O_B[nt]);
      }
    }
  }

  // ---- in-LDS combine of the 4 k-split partials ----
  __syncthreads();
  float* O_l = (float*)lds;                 // [8][16][68]
  float* mlp = (float*)(lds + 34816);       // [8][16][2]
#pragma unroll
  for (int nt = 0; nt < 4; ++nt)
#pragma unroll
    for (int r = 0; r < 4; ++r) {
      O_l[((w * 2 + 0) * 16 + 4 * g + r) * 68 + 16 * nt + l15] = O_A[nt][r];
      O_l[((w * 2 + 1) * 16 + 4 * g + r) * 68 + 16 * nt + l15] = O_B[nt][r];
    }
  if (g == 0) {
    mlp[((w * 2 + 0) * 16 + l15) * 2] = mA; mlp[((w * 2 + 0) * 16 + l15) * 2 + 1] = lA;
    mlp[((w * 2 + 1) * 16 + l15) * 2] = mB; mlp[((w * 2 + 1) * 16 + l15) * 2 + 1] = lB;
  }
  __syncthreads();

  const int q = tid >> 3;           // 0..31
  const int h0 = (tid & 7) * 8;     // 0..56
  const int qh = q >> 4, qr = q & 15;
  float M = -INFINITY;
#pragma unroll
  for (int s = 0; s < 4; ++s) M = fmaxf(M, mlp[((s * 2 + qh) * 16 + qr) * 2]);
  float L = 0.f;
  f32x4 a0 = zero, a1 = zero;
#pragma unroll
  for (int s = 0; s < 4; ++s) {
    const int rowi = (s * 2 + qh) * 16 + qr;
    const float wgt = __builtin_amdgcn_exp2f(mlp[rowi * 2] - M);
    L += wgt * mlp[rowi * 2 + 1];
    const f32x4 o0 = *(const f32x4*)&O_l[rowi * 68 + h0];
    const f32x4 o1 = *(const f32x4*)&O_l[rowi * 68 + h0 + 4];
#pragma unroll
    for (int i = 0; i < 4; ++i) { a0[i] += wgt * o0[i]; a1[i] += wgt * o1[i]; }
  }
  const float inv = 1.0f / L;
  float* ob = out + ((size_t)b * 4096 + qt * 32 + q) * 64 + h0;
  f32x4 r0 = {a0[0] * inv, a0[1] * inv, a0[2] * inv, a0[3] * inv};
  f32x4 r1 = {a1[0] * inv, a1[1] * inv, a1[2] * inv, a1[3] * inv};
  *(f32x4*)ob = r0;
  *(f32x4*)(ob + 4) = r1;
}

extern "C" void kernel_launch(void* const* d_in, const int* in_sizes, int n_in,
                              void* d_out, int out_size, void* d_ws, size_t ws_size,
                              hipStream_t stream) {
  const float* x  = (const float*)d_in[0];
  const float* Wq = (const float*)d_in[1];
  const float* bq = (const float*)d_in[2];
  const float* Wk = (const float*)d_in[3];
  const float* bk = (const float*)d_in[4];
  const float* Wv = (const float*)d_in[5];
  const float* bv = (const float*)d_in[6];

  char* ws = (char*)d_ws;
  unsigned short* WF = (unsigned short*)ws;                              // 384 KB
  unsigned short* Qb = (unsigned short*)(ws + (512u << 10));             // 2 MB
  unsigned short* KF = (unsigned short*)(ws + (512u << 10) + (2u << 20));// 2 MB
  unsigned short* VF = (unsigned short*)(ws + (512u << 10) + (4u << 20));// 2 MB
  float* out = (float*)d_out;

  hipLaunchKernelGGL(wt_kernel,    dim3(96),  dim3(256), 0, stream, Wq, Wk, Wv, WF);
  hipLaunchKernelGGL(proj_kernel,  dim3(256), dim3(256), 0, stream, x, WF, bq, bk, bv, Qb, KF, VF);
  hipLaunchKernelGGL(flash_kernel, dim3(512), dim3(256), 0, stream, Qb, KF, VF, out);
}